// Round 5
// baseline (280.771 us; speedup 1.0000x reference)
//
#include <hip/hip_runtime.h>

#define D 128
#define BM 64

typedef __attribute__((ext_vector_type(8))) short bf16x8;
typedef __attribute__((ext_vector_type(4))) float f32x4;

// ---- bf16 helpers (RNE) ---------------------------------------------------
__device__ __forceinline__ float bf2f(unsigned short u) {
    union { unsigned int i; float f; } v; v.i = ((unsigned int)u) << 16; return v.f;
}
__device__ __forceinline__ unsigned short f2bf(float f) {
    union { float f; unsigned int i; } v; v.f = f;
    unsigned int x = v.i;
    unsigned int r = (x + 0x7fffu + ((x >> 16) & 1u)) >> 16;   // RNE
    return (unsigned short)r;
}

// ---------------------------------------------------------------------------
// Kernel 0: zero counts + cursor (2n ints).
// ---------------------------------------------------------------------------
__global__ void gs_zero_i(int* __restrict__ p, int n) {
    int i = blockIdx.x * blockDim.x + threadIdx.x;
    int st = gridDim.x * blockDim.x;
    for (; i < n; i += st) p[i] = 0;
}

// ---------------------------------------------------------------------------
// Kernel 1: prep — per-block idx-dtype detect, decode+compact edges,
// inline histogram, x -> bf16, pack weights into MFMA-B-fragment order.
// B layout: chunk q in [0,4096): g=q&3, c=(q>>2)&127, s=q>>9;
//   Bp[q*8+j] = W[k=s*32+g*8+j][c]  (W = Wl for k<128 else Wr)
// ---------------------------------------------------------------------------
__global__ __launch_bounds__(256) void gs_prep(
    const float* __restrict__ x, const float* __restrict__ Wl,
    const float* __restrict__ Wr, const int* __restrict__ ei,
    unsigned short* __restrict__ x_bf, unsigned short* __restrict__ Bp,
    int* __restrict__ tgt32, int* __restrict__ nbr32,
    int* __restrict__ counts, int n, int E) {
    __shared__ int sflag;
    // dtype detect on the SAME window (first 64 edges) in every block:
    // int64 little-endian with values < 2^31 => all odd words zero.
    if (threadIdx.x < 64) {
        int lim = (E < 64) ? E : 64;
        int odd = (threadIdx.x < lim) ? ei[2 * threadIdx.x + 1] : 0;
        unsigned long long b = __ballot(odd != 0);
        if (threadIdx.x == 0) sflag = (b != 0ULL) ? 1 : 0;
    }
    __syncthreads();
    const int is32 = sflag;
    const int tid0 = blockIdx.x * 256 + threadIdx.x;
    const int stride = gridDim.x * 256;

    // decode + compact + histogram
    for (int e = tid0; e < E; e += stride) {
        int tgt, nbr;
        if (is32) { tgt = ei[e];     nbr = ei[E + e]; }
        else      { tgt = ei[2 * e]; nbr = ei[2 * (E + e)]; }
        int ok = ((unsigned)tgt < (unsigned)n) && ((unsigned)nbr < (unsigned)n);
        tgt32[e] = ok ? tgt : -1;
        nbr32[e] = nbr;
        if (ok) atomicAdd(&counts[tgt], 1);
    }
    // x -> bf16 (8 elems / iter)
    const int nch = n * (D / 8);
    for (int i = tid0; i < nch; i += stride) {
        const float4 a = *(const float4*)(x + (size_t)i * 8);
        const float4 b = *(const float4*)(x + (size_t)i * 8 + 4);
        unsigned short o[8] = {f2bf(a.x), f2bf(a.y), f2bf(a.z), f2bf(a.w),
                               f2bf(b.x), f2bf(b.y), f2bf(b.z), f2bf(b.w)};
        *(uint4*)(x_bf + (size_t)i * 8) = *(const uint4*)o;
    }
    // weight pack (4096 chunks)
    for (int q = tid0; q < 4096; q += stride) {
        int g = q & 3, c = (q >> 2) & 127, s = q >> 9;
        unsigned short o[8];
#pragma unroll
        for (int j = 0; j < 8; ++j) {
            int k = s * 32 + g * 8 + j;
            float w = (k < 128) ? Wl[k * 128 + c] : Wr[(k - 128) * 128 + c];
            o[j] = f2bf(w);
        }
        *(uint4*)(Bp + (size_t)q * 8) = *(const uint4*)o;
    }
}

// ---------------------------------------------------------------------------
// Kernel 2a/2b: two-level exclusive scan of counts.
// ---------------------------------------------------------------------------
__global__ __launch_bounds__(256) void gs_scanA(const int* __restrict__ counts,
                                                int* __restrict__ offs,
                                                int* __restrict__ partials, int n) {
    __shared__ int s[256];
    const int tid = threadIdx.x;
    const int i = blockIdx.x * 256 + tid;
    int v = (i < n) ? counts[i] : 0;
    s[tid] = v;
    __syncthreads();
    for (int off = 1; off < 256; off <<= 1) {
        int t = (tid >= off) ? s[tid - off] : 0;
        __syncthreads();
        s[tid] += t;
        __syncthreads();
    }
    if (i < n) offs[i] = s[tid] - v;
    if (tid == 255) partials[blockIdx.x] = s[255];
}

__global__ __launch_bounds__(512) void gs_scanB(int* __restrict__ partials, int nb) {
    __shared__ int s[512];
    const int tid = threadIdx.x;
    int v = (tid < nb) ? partials[tid] : 0;
    s[tid] = v;
    __syncthreads();
    for (int off = 1; off < 512; off <<= 1) {
        int t = (tid >= off) ? s[tid - off] : 0;
        __syncthreads();
        s[tid] += t;
        __syncthreads();
    }
    if (tid < nb) partials[tid] = s[tid] - v;
}

// ---------------------------------------------------------------------------
// Kernel 3: bin neighbors into CSR slots (compact inputs).
// ---------------------------------------------------------------------------
__global__ void gs_bin(const int* __restrict__ tgt32, const int* __restrict__ nbr32,
                       const int* __restrict__ offs, const int* __restrict__ partials,
                       int* __restrict__ cursor, int* __restrict__ sorted_nbr, int E) {
    int e = blockIdx.x * blockDim.x + threadIdx.x;
    if (e >= E) return;
    int tgt = tgt32[e];
    if (tgt < 0) return;
    int p = offs[tgt] + partials[tgt >> 8] + atomicAdd(&cursor[tgt], 1);
    sorted_nbr[p] = nbr32[e];
}

// ---------------------------------------------------------------------------
// Kernel 4: fused aggregate + MFMA GEMM + epilogue.
//  Phase A: stage x half of A-tile (chunks 0..15, XOR-swizzled LDS).
//  Phase B: wave w aggregates nodes w*16..w*16+15 (quarter-wave per neighbor,
//           fp32 accum, shfl-combine, bf16 mean straight into LDS chunks 16..31).
//  Phase C: K=256 MFMA GEMM, B frags from pre-packed global (L2-hot).
//  Frag maps (m89-verified): A row=l&15,k=(l>>4)*8+j; B k=(l>>4)*8+j,col=l&15;
//  C/D col=l&15, row=(l>>4)*4+r.
// ---------------------------------------------------------------------------
__global__ __launch_bounds__(256) void gs_fused(
    const unsigned short* __restrict__ x_bf, const int* __restrict__ sorted_nbr,
    const int* __restrict__ counts, const int* __restrict__ offs,
    const int* __restrict__ partials, const unsigned short* __restrict__ Bp,
    const float* __restrict__ bl, const float* __restrict__ br,
    float* __restrict__ out, int n) {
    __shared__ unsigned short sA[BM][256];   // 32 KB

    const int tid = threadIdx.x;
    const int wave = tid >> 6, lane = tid & 63;
    const int qw = lane >> 4, c = lane & 15;
    const int r0 = blockIdx.x * BM;

    // Phase A: stage x rows (chunks 0..15)
#pragma unroll
    for (int it = 0; it < 4; ++it) {
        int idx = it * 256 + tid;
        int row = idx >> 4, ch = idx & 15;
        int grow = r0 + row;
        uint4 val = make_uint4(0u, 0u, 0u, 0u);
        if (grow < n) val = *(const uint4*)(x_bf + (size_t)grow * D + ch * 8);
        int sch = ch ^ (row & 7);
        *(uint4*)((char*)&sA[0][0] + row * 512 + sch * 16) = val;
    }

    // Phase B: aggregate 16 nodes per wave. Preload cnt/start into lanes 0..15.
    {
        int myn = r0 + wave * 16 + c;
        int cnt_l = 0, start_l = 0;
        if (lane < 16 && myn < n) {
            cnt_l = counts[myn];
            start_l = offs[myn] + partials[myn >> 8];
        }
        for (int i = 0; i < 16; ++i) {
            const int cnt = __shfl(cnt_l, i, 64);
            const int start = __shfl(start_l, i, 64);
            float a[8] = {};
            for (int j = qw; j < cnt; j += 4) {
                int nbr = sorted_nbr[start + j];
                uint4 raw = *(const uint4*)(x_bf + (size_t)nbr * D + c * 8);
                const unsigned short* u = (const unsigned short*)&raw;
#pragma unroll
                for (int e = 0; e < 8; ++e) a[e] += bf2f(u[e]);
            }
#pragma unroll
            for (int e = 0; e < 8; ++e) {
                a[e] += __shfl_xor(a[e], 16, 64);
                a[e] += __shfl_xor(a[e], 32, 64);
            }
            if (qw == 0) {
                const float inv = (cnt > 0) ? (1.0f / (float)cnt) : 0.0f;
                unsigned short o[8];
#pragma unroll
                for (int e = 0; e < 8; ++e) o[e] = f2bf(a[e] * inv);
                int row = wave * 16 + i;
                int sch = (16 + c) ^ (row & 7);
                *(uint4*)((char*)&sA[0][0] + row * 512 + sch * 16) = *(const uint4*)o;
            }
        }
    }
    __syncthreads();

    // Phase C: GEMM. wave owns rows wave*16..+15, all 128 cols.
    f32x4 acc[8] = {};
    const int g = qw;
    const int arow = wave * 16 + c;
    const int axor = (arow & 7);
#pragma unroll
    for (int s = 0; s < 8; ++s) {
        bf16x8 afrag = *(const bf16x8*)((const char*)&sA[0][0] +
                                        arow * 512 + (((s * 4 + g) ^ axor) * 16));
#pragma unroll
        for (int f = 0; f < 8; ++f) {
            bf16x8 bfrag = *(const bf16x8*)(Bp + (size_t)(((s * 128 + f * 16 + c) * 4 + g) * 8));
            acc[f] = __builtin_amdgcn_mfma_f32_16x16x32_bf16(afrag, bfrag, acc[f], 0, 0, 0);
        }
    }

    // epilogue: bias + relu, row sumsq (16-lane shfl_xor), normalize, store
    float v[8][4];
    float sumsq[4] = {0.f, 0.f, 0.f, 0.f};
#pragma unroll
    for (int f = 0; f < 8; ++f) {
        float bb = bl[f * 16 + c] + br[f * 16 + c];
#pragma unroll
        for (int r = 0; r < 4; ++r) {
            float y = fmaxf(acc[f][r] + bb, 0.f);
            v[f][r] = y;
            sumsq[r] += y * y;
        }
    }
#pragma unroll
    for (int r = 0; r < 4; ++r) {
        float s = sumsq[r];
        s += __shfl_xor(s, 1, 64);
        s += __shfl_xor(s, 2, 64);
        s += __shfl_xor(s, 4, 64);
        s += __shfl_xor(s, 8, 64);
        sumsq[r] = 1.0f / (sqrtf(s) + 1e-6f);
    }
    const int baserow = r0 + wave * 16 + g * 4;
#pragma unroll
    for (int r = 0; r < 4; ++r) {
        int row = baserow + r;
        if (row < n) {
#pragma unroll
            for (int f = 0; f < 8; ++f)
                out[(size_t)row * D + f * 16 + c] = v[f][r] * sumsq[r];
        }
    }
}

// ---------------------------------------------------------------------------
extern "C" void kernel_launch(void* const* d_in, const int* in_sizes, int n_in,
                              void* d_out, int out_size, void* d_ws, size_t ws_size,
                              hipStream_t stream) {
    const float* x  = (const float*)d_in[0];
    const int*   ei = (const int*)d_in[1];
    const float* Wl = (const float*)d_in[2];
    const float* bl = (const float*)d_in[3];
    const float* Wr = (const float*)d_in[4];
    const float* br = (const float*)d_in[5];
    float* out = (float*)d_out;

    const int n = in_sizes[0] / D;
    const int E = in_sizes[1] / 2;
    const int nb = (n + 255) / 256;          // 391 for n=100000 (<=512)

    // workspace layout
    unsigned short* x_bf = (unsigned short*)d_ws;                   // n*128
    unsigned short* Bp   = x_bf + (size_t)n * D;                    // 32768
    int* counts   = (int*)(Bp + 32768);                             // n
    int* cursor   = counts + n;                                     // n
    int* offs     = cursor + n;                                     // n
    int* partials = offs + n;                                       // 512
    int* tgt32    = partials + 512;                                 // E
    int* nbr32    = tgt32 + E;                                      // E
    int* sorted   = nbr32 + E;                                      // E

    gs_zero_i<<<512, 256, 0, stream>>>(counts, 2 * n);              // counts+cursor
    gs_prep<<<4096, 256, 0, stream>>>(x, Wl, Wr, ei, x_bf, Bp, tgt32, nbr32, counts, n, E);
    gs_scanA<<<nb, 256, 0, stream>>>(counts, offs, partials, n);
    gs_scanB<<<1, 512, 0, stream>>>(partials, nb);
    gs_bin<<<(E + 255) / 256, 256, 0, stream>>>(tgt32, nbr32, offs, partials, cursor, sorted, E);
    gs_fused<<<(n + BM - 1) / BM, 256, 0, stream>>>(x_bf, sorted, counts, offs, partials, Bp, bl, br, out, n);
}

// Round 6
// 225.393 us; speedup vs baseline: 1.2457x; 1.2457x over previous
//
#include <hip/hip_runtime.h>

#define D 128
#define BM 64

typedef __attribute__((ext_vector_type(8))) short bf16x8;
typedef __attribute__((ext_vector_type(4))) float f32x4;

// ---- bf16 helpers (RNE) ---------------------------------------------------
__device__ __forceinline__ float bf2f(unsigned short u) {
    union { unsigned int i; float f; } v; v.i = ((unsigned int)u) << 16; return v.f;
}
__device__ __forceinline__ unsigned short f2bf(float f) {
    union { float f; unsigned int i; } v; v.f = f;
    unsigned int x = v.i;
    unsigned int r = (x + 0x7fffu + ((x >> 16) & 1u)) >> 16;   // RNE
    return (unsigned short)r;
}

// ---------------------------------------------------------------------------
// Kernel 1: prep — dtype detect, histogram+rank (packed (rank<<18)|tgt),
// x -> bf16, pack weights into MFMA-B-fragment order.
// B layout: chunk q in [0,4096): g=q&3, c=(q>>2)&127, s=q>>9;
//   Bp[q*8+j] = W[k=s*32+g*8+j][c]  (W = Wl for k<128 else Wr)
// ---------------------------------------------------------------------------
__global__ __launch_bounds__(256) void gs_prep(
    const float* __restrict__ x, const float* __restrict__ Wl,
    const float* __restrict__ Wr, const int* __restrict__ ei,
    unsigned short* __restrict__ x_bf, unsigned short* __restrict__ Bp,
    unsigned int* __restrict__ packed, int* __restrict__ counts,
    int* __restrict__ flag, int n, int E) {
    __shared__ int sflag;
    // dtype detect on the SAME window (first 64 edges) in every block:
    // int64 little-endian with values < 2^31 => all odd words zero.
    if (threadIdx.x < 64) {
        int lim = (E < 64) ? E : 64;
        int odd = (threadIdx.x < lim) ? ei[2 * threadIdx.x + 1] : 0;
        unsigned long long b = __ballot(odd != 0);
        if (threadIdx.x == 0) {
            sflag = (b != 0ULL) ? 1 : 0;
            if (blockIdx.x == 0) *flag = sflag;   // publish for gs_bin
        }
    }
    __syncthreads();
    const int is32 = sflag;
    const int tid0 = blockIdx.x * 256 + threadIdx.x;
    const int stride = gridDim.x * 256;

    // histogram + per-edge rank, packed (rank<<18)|tgt  (tgt < 2^18, deg < 2^14)
    for (int e = tid0; e < E; e += stride) {
        int tgt = is32 ? ei[e] : ei[2 * e];
        if ((unsigned)tgt < (unsigned)n) {
            unsigned int rank = (unsigned int)atomicAdd(&counts[tgt], 1);
            packed[e] = (rank << 18) | (unsigned int)tgt;
        } else {
            packed[e] = 0xFFFFFFFFu;   // tgt-field decodes >= n -> skipped
        }
    }
    // x -> bf16 (8 elems / iter)
    const int nch = n * (D / 8);
    for (int i = tid0; i < nch; i += stride) {
        const float4 a = *(const float4*)(x + (size_t)i * 8);
        const float4 b = *(const float4*)(x + (size_t)i * 8 + 4);
        unsigned short o[8] = {f2bf(a.x), f2bf(a.y), f2bf(a.z), f2bf(a.w),
                               f2bf(b.x), f2bf(b.y), f2bf(b.z), f2bf(b.w)};
        *(uint4*)(x_bf + (size_t)i * 8) = *(const uint4*)o;
    }
    // weight pack (4096 chunks)
    for (int q = tid0; q < 4096; q += stride) {
        int g = q & 3, c = (q >> 2) & 127, s = q >> 9;
        unsigned short o[8];
#pragma unroll
        for (int j = 0; j < 8; ++j) {
            int k = s * 32 + g * 8 + j;
            float w = (k < 128) ? Wl[k * 128 + c] : Wr[(k - 128) * 128 + c];
            o[j] = f2bf(w);
        }
        *(uint4*)(Bp + (size_t)q * 8) = *(const uint4*)o;
    }
}

// ---------------------------------------------------------------------------
// Kernel 2a/2b: two-level exclusive scan of counts.
// ---------------------------------------------------------------------------
__global__ __launch_bounds__(256) void gs_scanA(const int* __restrict__ counts,
                                                int* __restrict__ offs,
                                                int* __restrict__ partials, int n) {
    __shared__ int s[256];
    const int tid = threadIdx.x;
    const int i = blockIdx.x * 256 + tid;
    int v = (i < n) ? counts[i] : 0;
    s[tid] = v;
    __syncthreads();
    for (int off = 1; off < 256; off <<= 1) {
        int t = (tid >= off) ? s[tid - off] : 0;
        __syncthreads();
        s[tid] += t;
        __syncthreads();
    }
    if (i < n) offs[i] = s[tid] - v;
    if (tid == 255) partials[blockIdx.x] = s[255];
}

__global__ __launch_bounds__(512) void gs_scanB(int* __restrict__ partials, int nb) {
    __shared__ int s[512];
    const int tid = threadIdx.x;
    int v = (tid < nb) ? partials[tid] : 0;
    s[tid] = v;
    __syncthreads();
    for (int off = 1; off < 512; off <<= 1) {
        int t = (tid >= off) ? s[tid - off] : 0;
        __syncthreads();
        s[tid] += t;
        __syncthreads();
    }
    if (tid < nb) partials[tid] = s[tid] - v;
}

// ---------------------------------------------------------------------------
// Kernel 3: bin neighbors into CSR slots — NO atomics (rank precomputed).
// ---------------------------------------------------------------------------
__global__ void gs_bin(const unsigned int* __restrict__ packed,
                       const int* __restrict__ ei,
                       const int* __restrict__ offs, const int* __restrict__ partials,
                       int* __restrict__ sorted_nbr, const int* __restrict__ flag,
                       int E, int n) {
    int e = blockIdx.x * blockDim.x + threadIdx.x;
    if (e >= E) return;
    unsigned int v = packed[e];
    unsigned int tgt = v & 0x3FFFFu;
    if (tgt >= (unsigned)n) return;
    int nbr = (*flag) ? ei[E + e] : ei[2 * (E + e)];
    if ((unsigned)nbr >= (unsigned)n) return;
    int p = offs[tgt] + partials[tgt >> 8] + (int)(v >> 18);
    sorted_nbr[p] = nbr;
}

// ---------------------------------------------------------------------------
// Kernel 4: segmented mean over bf16 x. One wave per node; quarter-wave per
// neighbor (unroll 2: 8 rows in flight/wave). fp32 accum, bf16 mean out.
// ---------------------------------------------------------------------------
__global__ __launch_bounds__(256) void gs_agg(
    const int* __restrict__ sorted_nbr, const int* __restrict__ counts,
    const int* __restrict__ offs, const int* __restrict__ partials,
    const unsigned short* __restrict__ x_bf, unsigned short* __restrict__ agg_bf,
    int n) {
    int node = blockIdx.x * 4 + (threadIdx.x >> 6);
    if (node >= n) return;
    const int lane = threadIdx.x & 63;
    const int qw = lane >> 4, c = lane & 15;
    const int cnt = counts[node];
    const int start = offs[node] + partials[node >> 8];
    float a[8] = {};
    int j = qw;
    for (; j + 4 < cnt; j += 8) {
        int n1 = sorted_nbr[start + j];
        int n2 = sorted_nbr[start + j + 4];
        uint4 r1 = *(const uint4*)(x_bf + (size_t)n1 * D + c * 8);
        uint4 r2 = *(const uint4*)(x_bf + (size_t)n2 * D + c * 8);
        const unsigned short* u1 = (const unsigned short*)&r1;
        const unsigned short* u2 = (const unsigned short*)&r2;
#pragma unroll
        for (int e = 0; e < 8; ++e) a[e] += bf2f(u1[e]);
#pragma unroll
        for (int e = 0; e < 8; ++e) a[e] += bf2f(u2[e]);
    }
    if (j < cnt) {
        int n1 = sorted_nbr[start + j];
        uint4 r1 = *(const uint4*)(x_bf + (size_t)n1 * D + c * 8);
        const unsigned short* u1 = (const unsigned short*)&r1;
#pragma unroll
        for (int e = 0; e < 8; ++e) a[e] += bf2f(u1[e]);
    }
#pragma unroll
    for (int e = 0; e < 8; ++e) {
        a[e] += __shfl_xor(a[e], 16, 64);
        a[e] += __shfl_xor(a[e], 32, 64);
    }
    if (qw == 0) {
        const float inv = (cnt > 0) ? (1.0f / (float)cnt) : 0.0f;
        unsigned short o[8];
#pragma unroll
        for (int e = 0; e < 8; ++e) o[e] = f2bf(a[e] * inv);
        *(uint4*)(agg_bf + (size_t)node * D + c * 8) = *(const uint4*)o;
    }
}

// ---------------------------------------------------------------------------
// Kernel 5: fused MFMA GEMM  out = normalize(relu([x|agg] @ [Wl;Wr] + bl+br))
// M-tile 64 rows, 4 waves; wave w owns rows w*16..w*16+15, all 128 cols.
// A staged in LDS (XOR-swizzled 16B chunks); B frags pre-packed (L2-hot).
// Frag maps (m89-verified): A row=l&15,k=(l>>4)*8+j; B k=(l>>4)*8+j,col=l&15;
// C/D col=l&15, row=(l>>4)*4+r.
// ---------------------------------------------------------------------------
__global__ __launch_bounds__(256) void gs_fused(
    const unsigned short* __restrict__ x_bf, const unsigned short* __restrict__ agg_bf,
    const unsigned short* __restrict__ Bp,
    const float* __restrict__ bl, const float* __restrict__ br,
    float* __restrict__ out, int n) {
    __shared__ unsigned short sA[BM][256];   // 32 KB

    const int tid = threadIdx.x;
    const int wave = tid >> 6, lane = tid & 63;
    const int g = lane >> 4, c = lane & 15;
    const int r0 = blockIdx.x * BM;

    // stage A: 64 rows x 32 chunks(16B). chunk<16 from x_bf, else agg_bf.
#pragma unroll
    for (int it = 0; it < 8; ++it) {
        int idx = it * 256 + tid;
        int row = idx >> 5, ch = idx & 31;
        int grow = r0 + row;
        uint4 val = make_uint4(0u, 0u, 0u, 0u);
        if (grow < n) {
            const unsigned short* src = (ch < 16)
                ? (x_bf + (size_t)grow * D + ch * 8)
                : (agg_bf + (size_t)grow * D + (ch - 16) * 8);
            val = *(const uint4*)src;
        }
        int sch = ch ^ (row & 7);
        *(uint4*)((char*)&sA[0][0] + row * 512 + sch * 16) = val;
    }
    __syncthreads();

    f32x4 acc[8] = {};
    const int arow = wave * 16 + c;
    const int axor = (arow & 7);
#pragma unroll
    for (int s = 0; s < 8; ++s) {
        bf16x8 afrag = *(const bf16x8*)((const char*)&sA[0][0] +
                                        arow * 512 + (((s * 4 + g) ^ axor) * 16));
#pragma unroll
        for (int f = 0; f < 8; ++f) {
            bf16x8 bfrag = *(const bf16x8*)(Bp + (size_t)(((s * 128 + f * 16 + c) * 4 + g) * 8));
            acc[f] = __builtin_amdgcn_mfma_f32_16x16x32_bf16(afrag, bfrag, acc[f], 0, 0, 0);
        }
    }

    // epilogue: bias + relu, row sumsq (16-lane shfl_xor), normalize, store
    float v[8][4];
    float sumsq[4] = {0.f, 0.f, 0.f, 0.f};
#pragma unroll
    for (int f = 0; f < 8; ++f) {
        float bb = bl[f * 16 + c] + br[f * 16 + c];
#pragma unroll
        for (int r = 0; r < 4; ++r) {
            float y = fmaxf(acc[f][r] + bb, 0.f);
            v[f][r] = y;
            sumsq[r] += y * y;
        }
    }
#pragma unroll
    for (int r = 0; r < 4; ++r) {
        float s = sumsq[r];
        s += __shfl_xor(s, 1, 64);
        s += __shfl_xor(s, 2, 64);
        s += __shfl_xor(s, 4, 64);
        s += __shfl_xor(s, 8, 64);
        sumsq[r] = 1.0f / (sqrtf(s) + 1e-6f);
    }
    const int baserow = r0 + wave * 16 + g * 4;
#pragma unroll
    for (int r = 0; r < 4; ++r) {
        int row = baserow + r;
        if (row < n) {
#pragma unroll
            for (int f = 0; f < 8; ++f)
                out[(size_t)row * D + f * 16 + c] = v[f][r] * sumsq[r];
        }
    }
}

// ---------------------------------------------------------------------------
extern "C" void kernel_launch(void* const* d_in, const int* in_sizes, int n_in,
                              void* d_out, int out_size, void* d_ws, size_t ws_size,
                              hipStream_t stream) {
    const float* x  = (const float*)d_in[0];
    const int*   ei = (const int*)d_in[1];
    const float* Wl = (const float*)d_in[2];
    const float* bl = (const float*)d_in[3];
    const float* Wr = (const float*)d_in[4];
    const float* br = (const float*)d_in[5];
    float* out = (float*)d_out;

    const int n = in_sizes[0] / D;
    const int E = in_sizes[1] / 2;
    const int nb = (n + 255) / 256;          // 391 for n=100000 (<=512)

    // workspace layout (~58.6 MB)
    unsigned short* x_bf   = (unsigned short*)d_ws;                 // n*128
    unsigned short* agg_bf = x_bf + (size_t)n * D;                  // n*128
    unsigned short* Bp     = agg_bf + (size_t)n * D;                // 32768
    int* counts   = (int*)(Bp + 32768);                             // n
    int* offs     = counts + n;                                     // n
    int* partials = offs + n;                                       // 512
    int* flag     = partials + 512;                                 // 4 pad
    unsigned int* packed = (unsigned int*)(flag + 4);               // E
    int* sorted   = (int*)(packed + E);                             // E

    hipMemsetAsync(counts, 0, (size_t)n * sizeof(int), stream);
    gs_prep<<<4096, 256, 0, stream>>>(x, Wl, Wr, ei, x_bf, Bp, packed, counts, flag, n, E);
    gs_scanA<<<nb, 256, 0, stream>>>(counts, offs, partials, n);
    gs_scanB<<<1, 512, 0, stream>>>(partials, nb);
    gs_bin<<<(E + 255) / 256, 256, 0, stream>>>(packed, ei, offs, partials, sorted, flag, E, n);
    gs_agg<<<(n + 3) / 4, 256, 0, stream>>>(sorted, counts, offs, partials, x_bf, agg_bf, n);
    gs_fused<<<(n + BM - 1) / BM, 256, 0, stream>>>(x_bf, agg_bf, Bp, bl, br, out, n);
}